// Round 6
// baseline (775.685 us; speedup 1.0000x reference)
//
#include <hip/hip_runtime.h>
#include <hip/hip_bf16.h>
#include <math.h>

// 2-layer ReLU RNN, B=256, T=1000 (input 800 + zero pad), H=128, F=5.
// R6: 256 blocks x 256 threads (4 waves). R5 post-mortem: DS pipe saturated
// by B-replication (80 b128/CU-step ~ 960 cyc > 504-cyc MFMA floor). Waves
// scale DS traffic (replication is per-wave), MFMA/SIMD is invariant ->
// halve waves: 4 waves x 2 rowtiles x 3 matvecs = 26 MFMA/wave (6 chains,
// interleaved kt-round-robin). DS now ~34 reads ~400 cyc < MFMA 504.
//   L0 : h0[s]  = relu(Whh0.h0[s-1] + Wih0.x[s] + b0)
//   L1i: A[s-1] = Wih1.h0[s-1] + b1          (shares B with L0)
//   L1h: h1[s-2]= relu(A[s-2] + Whh1.h1[s-3]) (C-init = A_f read)
// x-read masked to q4==0 lanes (A-frag zero elsewhere); A_f read masked to
// m==0 lanes (only col-0 D survives; columns independent, writes guarded).
// No global ops in loop. Layouts (m89/m91): A[m=lane&15][k=(lane>>4)*8+j];
// C/D col=lane&15, row=(lane>>4)*4+reg.

#define TT    1000
#define TIN   800
#define HD    128
#define NF    5
#define BATCH 256

typedef float f32x4 __attribute__((ext_vector_type(4)));
typedef short s16x8 __attribute__((ext_vector_type(8)));

__device__ __forceinline__ unsigned short f2bf(float f) {
    union { float f; unsigned int u; } c; c.f = f;
    unsigned int r = (c.u + 0x7FFFu + ((c.u >> 16) & 1u)) >> 16;  // RNE
    return (unsigned short)r;
}
__device__ __forceinline__ float bf2f(unsigned short h) {
    union { unsigned int u; float f; } c; c.u = ((unsigned int)h) << 16;
    return c.f;
}
__device__ __forceinline__ unsigned pk2bf(float a, float b) {
    union { __hip_bfloat162 h; unsigned u; } c;
    c.h = __float22bfloat162_rn(make_float2(a, b));   // v_cvt_pk_bf16_f32
    return c.u;
}

__global__ __launch_bounds__(256, 1) void rnn_mfma(
    const float* __restrict__ x,        // [256,800,5]
    const float* __restrict__ h_state,  // [2,256,128]
    const float* __restrict__ w_ih0,    // [128,5]
    const float* __restrict__ w_hh0,    // [128,128]
    const float* __restrict__ b_ih0,    // [128]
    const float* __restrict__ b_hh0,    // [128]
    const float* __restrict__ w_ih1,    // [128,128]
    const float* __restrict__ w_hh1,    // [128,128]
    const float* __restrict__ b_ih1,    // [128]
    const float* __restrict__ b_hh1,    // [128]
    const float* __restrict__ w_out,    // [1,128]
    const float* __restrict__ b_out,    // [1]
    float* __restrict__ out)            // [204800 y] ++ [65536 final states]
{
    __shared__ __align__(16) unsigned short x_bf[TIN * 8];  // 12.8 KB
    __shared__ __align__(16) unsigned short h0b[2][HD];
    __shared__ __align__(16) unsigned short h1b[2][HD];
    __shared__ __align__(16) float A_f[2][HD];              // pre-act (+b1)
    __shared__ __align__(16) unsigned short ring[16][HD];   // h1 history bf16
    __shared__ float wout_lds[HD];
    __shared__ float y_lds[TIN];                            // 3.2 KB

    const int tid = threadIdx.x;
    const int bb  = blockIdx.x;
    const int wv  = tid >> 6;          // 0..3 : rows 32*wv .. 32*wv+31
    const int l   = tid & 63;
    const int m   = l & 15;            // A row within tile / C col
    const int q4  = l >> 4;
    const bool wr = (m == 0);          // C col 0 -> writer lane
    const int r0  = 32 * wv + 4 * q4;  // rt0 C/D row base; rt1: +16

    // ---- stage x as bf16, stride 8; zero the never-written LDS buffers ----
    for (int i = tid; i < TIN * 8; i += 256) x_bf[i] = 0;
    __syncthreads();
    for (int i = tid; i < TIN * NF; i += 256) {
        int t = i / 5, f = i - 5 * t;
        x_bf[t * 8 + f] = f2bf(x[bb * (TIN * NF) + i]);
    }
    if (tid < HD) {
        h0b[0][tid] = f2bf(h_state[bb * HD + tid]);
        h1b[0][tid] = f2bf(h_state[BATCH * HD + bb * HD + tid]);
        h0b[1][tid] = 0; h1b[1][tid] = 0;
        A_f[0][tid] = 0.f; A_f[1][tid] = 0.f;
    } else if (tid < 2 * HD) {
        wout_lds[tid - HD] = w_out[tid - HD];
    }

    // ---- resident A fragments: F[matrix][rowtile][ktile] ----
    s16x8 F[3][2][4];
    #pragma unroll
    for (int rt = 0; rt < 2; ++rt) {
        const int row = 32 * wv + 16 * rt + m;
        #pragma unroll
        for (int kt = 0; kt < 4; ++kt) {
            const float* p0 = w_hh0 + row * HD + kt * 32 + q4 * 8;
            const float* p1 = w_ih1 + row * HD + kt * 32 + q4 * 8;
            const float* p2 = w_hh1 + row * HD + kt * 32 + q4 * 8;
            s16x8 a0, a1, a2;
            #pragma unroll
            for (int j = 0; j < 8; ++j) {
                a0[j] = (short)f2bf(p0[j]);
                a1[j] = (short)f2bf(p1[j]);
                a2[j] = (short)f2bf(p2[j]);
            }
            F[0][rt][kt] = a0; F[1][rt][kt] = a1; F[2][rt][kt] = a2;
        }
    }
    s16x8 Fx[2];
    #pragma unroll
    for (int rt = 0; rt < 2; ++rt) {
        s16x8 a = {0,0,0,0,0,0,0,0};
        if (q4 == 0) {
            const int row = 32 * wv + 16 * rt + m;
            #pragma unroll
            for (int j = 0; j < NF; ++j) a[j] = (short)f2bf(w_ih0[row * NF + j]);
        }
        Fx[rt] = a;
    }
    f32x4 b0a, b0b, b1a, b1b;
    #pragma unroll
    for (int j = 0; j < 4; ++j) {
        b0a[j] = b_ih0[r0 + j]      + b_hh0[r0 + j];
        b0b[j] = b_ih0[r0 + 16 + j] + b_hh0[r0 + 16 + j];
        b1a[j] = b_ih1[r0 + j]      + b_hh1[r0 + j];
        b1b[j] = b_ih1[r0 + 16 + j] + b_hh1[r0 + 16 + j];
    }
    const float bout = b_out[0];

    f32x4 hfin0a = {0,0,0,0}, hfin0b = {0,0,0,0};
    f32x4 hfin1a = {0,0,0,0}, hfin1b = {0,0,0,0};
    s16x8 Bx = {0,0,0,0,0,0,0,0};
    f32x4 pre0 = {0,0,0,0}, pre1 = {0,0,0,0};

    __syncthreads();

    #pragma unroll 2
    for (int s = 0; s < TT + 2; ++s) {
        const int p = s & 1;
        const int q = p ^ 1;
        const unsigned short* h0p = h0b[p];
        const unsigned short* h1p = h1b[p];

        // ---- all LDS reads up front ----
        s16x8 B0 = *(const s16x8*)(h0p +      q4 * 8);
        s16x8 B1 = *(const s16x8*)(h0p + 32 + q4 * 8);
        s16x8 B2 = *(const s16x8*)(h0p + 64 + q4 * 8);
        s16x8 B3 = *(const s16x8*)(h0p + 96 + q4 * 8);
        s16x8 C0 = *(const s16x8*)(h1p +      q4 * 8);
        s16x8 C1 = *(const s16x8*)(h1p + 32 + q4 * 8);
        s16x8 C2 = *(const s16x8*)(h1p + 64 + q4 * 8);
        s16x8 C3 = *(const s16x8*)(h1p + 96 + q4 * 8);
        if (q4 == 0 && s < TIN) Bx = *(const s16x8*)(x_bf + s * 8);
        if (m == 0) {
            pre0 = *(const f32x4*)(&A_f[p][r0]);
            pre1 = *(const f32x4*)(&A_f[p][r0 + 16]);
        }

        // ---- 6 independent MFMA chains, kt round-robin ----
        f32x4 D0 = b0a, D1 = b0b, D2 = b1a, D3 = b1b, D4 = pre0, D5 = pre1;
        D0 = __builtin_amdgcn_mfma_f32_16x16x32_bf16(F[0][0][0], B0, D0, 0, 0, 0);
        D1 = __builtin_amdgcn_mfma_f32_16x16x32_bf16(F[0][1][0], B0, D1, 0, 0, 0);
        D2 = __builtin_amdgcn_mfma_f32_16x16x32_bf16(F[1][0][0], B0, D2, 0, 0, 0);
        D3 = __builtin_amdgcn_mfma_f32_16x16x32_bf16(F[1][1][0], B0, D3, 0, 0, 0);
        D4 = __builtin_amdgcn_mfma_f32_16x16x32_bf16(F[2][0][0], C0, D4, 0, 0, 0);
        D5 = __builtin_amdgcn_mfma_f32_16x16x32_bf16(F[2][1][0], C0, D5, 0, 0, 0);
        D0 = __builtin_amdgcn_mfma_f32_16x16x32_bf16(F[0][0][1], B1, D0, 0, 0, 0);
        D1 = __builtin_amdgcn_mfma_f32_16x16x32_bf16(F[0][1][1], B1, D1, 0, 0, 0);
        D2 = __builtin_amdgcn_mfma_f32_16x16x32_bf16(F[1][0][1], B1, D2, 0, 0, 0);
        D3 = __builtin_amdgcn_mfma_f32_16x16x32_bf16(F[1][1][1], B1, D3, 0, 0, 0);
        D4 = __builtin_amdgcn_mfma_f32_16x16x32_bf16(F[2][0][1], C1, D4, 0, 0, 0);
        D5 = __builtin_amdgcn_mfma_f32_16x16x32_bf16(F[2][1][1], C1, D5, 0, 0, 0);
        D0 = __builtin_amdgcn_mfma_f32_16x16x32_bf16(F[0][0][2], B2, D0, 0, 0, 0);
        D1 = __builtin_amdgcn_mfma_f32_16x16x32_bf16(F[0][1][2], B2, D1, 0, 0, 0);
        D2 = __builtin_amdgcn_mfma_f32_16x16x32_bf16(F[1][0][2], B2, D2, 0, 0, 0);
        D3 = __builtin_amdgcn_mfma_f32_16x16x32_bf16(F[1][1][2], B2, D3, 0, 0, 0);
        D4 = __builtin_amdgcn_mfma_f32_16x16x32_bf16(F[2][0][2], C2, D4, 0, 0, 0);
        D5 = __builtin_amdgcn_mfma_f32_16x16x32_bf16(F[2][1][2], C2, D5, 0, 0, 0);
        D0 = __builtin_amdgcn_mfma_f32_16x16x32_bf16(F[0][0][3], B3, D0, 0, 0, 0);
        D1 = __builtin_amdgcn_mfma_f32_16x16x32_bf16(F[0][1][3], B3, D1, 0, 0, 0);
        D2 = __builtin_amdgcn_mfma_f32_16x16x32_bf16(F[1][0][3], B3, D2, 0, 0, 0);
        D3 = __builtin_amdgcn_mfma_f32_16x16x32_bf16(F[1][1][3], B3, D3, 0, 0, 0);
        D4 = __builtin_amdgcn_mfma_f32_16x16x32_bf16(F[2][0][3], C3, D4, 0, 0, 0);
        D5 = __builtin_amdgcn_mfma_f32_16x16x32_bf16(F[2][1][3], C3, D5, 0, 0, 0);
        if (s < TIN) {
            D0 = __builtin_amdgcn_mfma_f32_16x16x32_bf16(Fx[0], Bx, D0, 0, 0, 0);
            D1 = __builtin_amdgcn_mfma_f32_16x16x32_bf16(Fx[1], Bx, D1, 0, 0, 0);
        }

        // ---- epilogue (writer lanes: col 0) ----
        if (wr) {
            if (s < TT) {
                f32x4 v0, v1;
                #pragma unroll
                for (int j = 0; j < 4; ++j) {
                    v0[j] = fmaxf(D0[j], 0.f);
                    v1[j] = fmaxf(D1[j], 0.f);
                }
                *(uint2*)(h0b[q] + r0)      = make_uint2(pk2bf(v0[0], v0[1]), pk2bf(v0[2], v0[3]));
                *(uint2*)(h0b[q] + r0 + 16) = make_uint2(pk2bf(v1[0], v1[1]), pk2bf(v1[2], v1[3]));
                if (s == TT - 1) { hfin0a = v0; hfin0b = v1; }
            }
            if (s <= TT) {
                *(f32x4*)(&A_f[q][r0])      = D2;
                *(f32x4*)(&A_f[q][r0 + 16]) = D3;
            }
            if (s >= 2) {
                const int u = s - 2;
                f32x4 v0, v1;
                #pragma unroll
                for (int j = 0; j < 4; ++j) {
                    v0[j] = fmaxf(D4[j], 0.f);
                    v1[j] = fmaxf(D5[j], 0.f);
                }
                uint2 pk0 = make_uint2(pk2bf(v0[0], v0[1]), pk2bf(v0[2], v0[3]));
                uint2 pk1 = make_uint2(pk2bf(v1[0], v1[1]), pk2bf(v1[2], v1[3]));
                *(uint2*)(h1b[q] + r0)      = pk0;
                *(uint2*)(h1b[q] + r0 + 16) = pk1;
                if (u < TIN) {
                    *(uint2*)(ring[u & 15] + r0)      = pk0;
                    *(uint2*)(ring[u & 15] + r0 + 16) = pk1;
                }
                if (u == TT - 1) { hfin1a = v0; hfin1b = v1; }
            }
        }

        // ---- batched y-dots (all 4 waves), every 8th step ----
        if (s >= 10 && s <= 802 && ((s - 2) & 7) == 0) {
            const int u  = (s - 10) + (tid >> 5);
            const int l5 = tid & 31;
            const unsigned short* hr = ring[u & 15];
            float v = bf2f(hr[l5      ]) * wout_lds[l5      ]
                    + bf2f(hr[l5 + 32]) * wout_lds[l5 + 32]
                    + bf2f(hr[l5 + 64]) * wout_lds[l5 + 64]
                    + bf2f(hr[l5 + 96]) * wout_lds[l5 + 96];
            v += __shfl_xor(v, 16, 64);
            v += __shfl_xor(v,  8, 64);
            v += __shfl_xor(v,  4, 64);
            v += __shfl_xor(v,  2, 64);
            v += __shfl_xor(v,  1, 64);
            if (l5 == 0) y_lds[u] = 1.f / (1.f + expf(-(v + bout)));
        }
        __syncthreads();
    }

    // ---- epilogue: single global dump ----
    for (int i = tid; i < TIN; i += 256)
        out[bb * TIN + i] = y_lds[i];
    if (wr) {
        *(f32x4*)(out + TIN * BATCH + bb * HD + r0)                   = hfin0a;
        *(f32x4*)(out + TIN * BATCH + bb * HD + r0 + 16)              = hfin0b;
        *(f32x4*)(out + TIN * BATCH + BATCH * HD + bb * HD + r0)      = hfin1a;
        *(f32x4*)(out + TIN * BATCH + BATCH * HD + bb * HD + r0 + 16) = hfin1b;
    }
}

extern "C" void kernel_launch(void* const* d_in, const int* in_sizes, int n_in,
                              void* d_out, int out_size, void* d_ws, size_t ws_size,
                              hipStream_t stream) {
    (void)in_sizes; (void)n_in; (void)d_ws; (void)ws_size; (void)out_size;
    rnn_mfma<<<dim3(BATCH), dim3(256), 0, stream>>>(
        (const float*)d_in[0],  (const float*)d_in[1],
        (const float*)d_in[2],  (const float*)d_in[3],
        (const float*)d_in[4],  (const float*)d_in[5],
        (const float*)d_in[6],  (const float*)d_in[7],
        (const float*)d_in[8],  (const float*)d_in[9],
        (const float*)d_in[10], (const float*)d_in[11],
        (float*)d_out);
}

// Round 7
// 526.815 us; speedup vs baseline: 1.4724x; 1.4724x over previous
//
#include <hip/hip_runtime.h>
#include <math.h>

// 2-layer ReLU RNN, B=256, T=1000 (input 800 + zero pad), H=128, F=5.
// R7: back to the verified R2 skeleton (768 thr = 3 matvec groups x 256,
// 8x8 tiles, XOR-linear row map, all-DPP reduction, 1 barrier/step), but
// inner product via v_dot2_f32_f16 (__builtin_amdgcn_fdot2): 2 MAC/instr,
// fp32 accumulate, full VALU rate. Why: MFMA-GEMV (R3-R6) is structurally
// capped at ~504 cyc/SIMD-step (15/16 of each tile wasted on broadcast B)
// + 16x LDS B-replication; the dot2 VALU floor is 96 cyc/SIMD-step with
// zero replication. fp16 storage of h/W also beats bf16 precision (10-bit
// mantissa): expect absmax ~1e-3 vs 3.9e-3.
// Weights resident as packed half2 (32 VGPRs/thread). h in LDS as fp16;
// per-thread h-read = 16 B (one b128). x kept fp32 (layer-0 x-term and all
// bias adds in fp32, as R2). No global ops inside the step loop.

#define TT    1000
#define TIN   800
#define HD    128
#define NF    5
#define BATCH 256

typedef _Float16 h16x2 __attribute__((ext_vector_type(2)));
typedef _Float16 h16x8 __attribute__((ext_vector_type(8)));

template<int CTRL>
__device__ __forceinline__ float dpp_mov(float v) {
    union { float f; int i; } u, r;
    u.f = v;
    r.i = __builtin_amdgcn_update_dpp(0, u.i, CTRL, 0xF, 0xF, true);
    return r.f;
}

__global__ __launch_bounds__(768, 3) void rnn_dot2(
    const float* __restrict__ x,        // [256,800,5]
    const float* __restrict__ h_state,  // [2,256,128]
    const float* __restrict__ w_ih0,    // [128,5]
    const float* __restrict__ w_hh0,    // [128,128]
    const float* __restrict__ b_ih0,    // [128]
    const float* __restrict__ b_hh0,    // [128]
    const float* __restrict__ w_ih1,    // [128,128]
    const float* __restrict__ w_hh1,    // [128,128]
    const float* __restrict__ b_ih1,    // [128]
    const float* __restrict__ b_hh1,    // [128]
    const float* __restrict__ w_out,    // [1,128]
    const float* __restrict__ b_out,    // [1]
    float* __restrict__ out)            // [204800 y] ++ [65536 final states]
{
    __shared__ float x_lds[TIN * 8];                    // fp32, stride 8
    __shared__ __align__(16) _Float16 h0h[2][HD];
    __shared__ __align__(16) _Float16 h1h[2][HD];
    __shared__ float A_f[2][HD];                        // fp32 pre-activation
    __shared__ __align__(16) _Float16 ring[16][HD];     // h1 history (fp16)
    __shared__ float wout_lds[HD];
    __shared__ float y_lds[TIN];

    const int tid = threadIdx.x;
    const int bb  = blockIdx.x;         // batch element
    const int grp = tid >> 8;           // 0,1,2 : matvec engine
    const int lt  = tid & 255;
    const int c   = lt & 15;            // col chunk / reduction lane
    const int rg  = lt >> 4;            // row group (8 rows)
    const int g   = (4 * (c & 1)) ^ (2 * ((c >> 1) & 1)) ^ (7 * ((c >> 2) & 1));
    const int row = rg * 8 + g;         // row this thread finalizes
    const bool writer = (c & 8) == 0;

    // ---- stage x[bb] into LDS (fp32, stride 8) ----
    for (int i = tid; i < TIN * NF; i += 768) {
        int t = i / 5, f = i - 5 * t;
        x_lds[t * 8 + f] = x[bb * (TIN * NF) + i];
    }
    if (tid < HD) {
        h0h[0][tid] = (_Float16)h_state[bb * HD + tid];
        h1h[0][tid] = (_Float16)h_state[BATCH * HD + bb * HD + tid];
    } else if (tid < 2 * HD) {
        wout_lds[tid - HD] = w_out[tid - HD];
    }

    // ---- weights: my 8x8 tile, rows rg*8+(j^g), cols c*8..c*8+7, fp16 ----
    const float* Wsrc = (grp == 0) ? w_hh0 : ((grp == 1) ? w_ih1 : w_hh1);
    h16x2 wp[8][4];
    #pragma unroll
    for (int j = 0; j < 8; ++j) {
        const float* rp = Wsrc + (rg * 8 + (j ^ g)) * HD + c * 8;
        #pragma unroll
        for (int t = 0; t < 4; ++t) {
            h16x2 w2 = { (_Float16)rp[2 * t], (_Float16)rp[2 * t + 1] };
            wp[j][t] = w2;
        }
    }
    float wih0r[NF];
    float bias = 0.f;
    if (grp == 0) {
        #pragma unroll
        for (int f = 0; f < NF; ++f) wih0r[f] = w_ih0[row * NF + f];
        bias = b_ih0[row] + b_hh0[row];
    } else if (grp == 2) {
        bias = b_ih1[row] + b_hh1[row];
    }
    const float bout = b_out[0];

    float hfin = 0.f;   // grp0 writer: h0[999]; grp2 writer: h1[999]

    __syncthreads();

    // 8x8 tile matvec via fdot2 + all-DPP 16-lane reduction (R2-verified).
    auto matvec = [&](const _Float16* hbuf) -> float {
        h16x8 hv = *(const h16x8*)(hbuf + c * 8);
        h16x2 hp0 = { hv[0], hv[1] }, hp1 = { hv[2], hv[3] };
        h16x2 hp2 = { hv[4], hv[5] }, hp3 = { hv[6], hv[7] };
        float a[8];
        #pragma unroll
        for (int j = 0; j < 8; ++j) {
            float aj;
            aj = __builtin_amdgcn_fdot2(wp[j][0], hp0, 0.f, false);
            aj = __builtin_amdgcn_fdot2(wp[j][1], hp1, aj,  false);
            aj = __builtin_amdgcn_fdot2(wp[j][2], hp2, aj,  false);
            aj = __builtin_amdgcn_fdot2(wp[j][3], hp3, aj,  false);
            a[j] = aj;
        }
        a[0] += dpp_mov<0xB1>(a[4]);   // xor1
        a[1] += dpp_mov<0xB1>(a[5]);
        a[2] += dpp_mov<0xB1>(a[6]);
        a[3] += dpp_mov<0xB1>(a[7]);
        a[0] += dpp_mov<0x4E>(a[2]);   // xor2
        a[1] += dpp_mov<0x4E>(a[3]);
        a[0] += dpp_mov<0x140>(a[1]);  // xor15 (row_mirror)
        a[0] += dpp_mov<0x128>(a[0]);  // xor8  (row_ror:8)
        return a[0];
    };

    #pragma unroll 2
    for (int s = 0; s < TT + 2; ++s) {
        const int p = s & 1;
        const int q = p ^ 1;

        if (grp == 0) {
            // h0[s] = relu(Whh0.h0[s-1] + Wih0.x[s] + b)
            if (s < TT) {
                float acc = matvec(h0h[p]);
                float v = acc + bias;
                if (s < TIN) {
                    const float* xr = &x_lds[s * 8];
                    float4 xv = *(const float4*)xr;
                    float x4 = xr[4];
                    v = fmaf(wih0r[0], xv.x, v);
                    v = fmaf(wih0r[1], xv.y, v);
                    v = fmaf(wih0r[2], xv.z, v);
                    v = fmaf(wih0r[3], xv.w, v);
                    v = fmaf(wih0r[4], x4,   v);
                }
                v = fmaxf(v, 0.f);
                if (writer) {
                    h0h[q][row] = (_Float16)v;
                    if (s == TT - 1) hfin = v;
                }
            }
        } else if (grp == 1) {
            // A[s-1] = Wih1 . h0[s-1]  (fp32)
            if (s <= TT) {
                float acc = matvec(h0h[p]);
                if (writer) A_f[q][row] = acc;
            }
            // batched y-dots: 8 sigmoids per visit, every 8th step
            if (s >= 10 && s <= 802 && ((s - 2) & 7) == 0) {
                const int u  = (s - 10) + (lt >> 5);
                const int l5 = lt & 31;
                const _Float16* hr = ring[u & 15];
                float v = (float)hr[l5      ] * wout_lds[l5      ]
                        + (float)hr[l5 + 32] * wout_lds[l5 + 32]
                        + (float)hr[l5 + 64] * wout_lds[l5 + 64]
                        + (float)hr[l5 + 96] * wout_lds[l5 + 96];
                v += __shfl_xor(v, 16, 64);
                v += __shfl_xor(v,  8, 64);
                v += __shfl_xor(v,  4, 64);
                v += __shfl_xor(v,  2, 64);
                v += __shfl_xor(v,  1, 64);
                if (l5 == 0) y_lds[u] = 1.f / (1.f + expf(-(v + bout)));
            }
        } else {
            // h1[s-2] = relu(A[s-2] + Whh1.h1[s-3] + b)
            if (s >= 2) {
                const int u = s - 2;
                float acc = matvec(h1h[p]);
                float v = fmaxf(acc + bias + A_f[p][row], 0.f);
                if (writer) {
                    _Float16 vh = (_Float16)v;
                    h1h[q][row] = vh;
                    if (u < TIN) ring[u & 15][row] = vh;
                    if (u == TT - 1) hfin = v;
                }
            }
        }
        __syncthreads();
    }

    // ---- epilogue: single global dump ----
    for (int i = tid; i < TIN; i += 768)
        out[bb * TIN + i] = y_lds[i];
    if (grp == 0 && writer)
        out[TIN * BATCH + bb * HD + row] = hfin;
    if (grp == 2 && writer)
        out[TIN * BATCH + BATCH * HD + bb * HD + row] = hfin;
}

extern "C" void kernel_launch(void* const* d_in, const int* in_sizes, int n_in,
                              void* d_out, int out_size, void* d_ws, size_t ws_size,
                              hipStream_t stream) {
    (void)in_sizes; (void)n_in; (void)d_ws; (void)ws_size; (void)out_size;
    rnn_dot2<<<dim3(BATCH), dim3(768), 0, stream>>>(
        (const float*)d_in[0],  (const float*)d_in[1],
        (const float*)d_in[2],  (const float*)d_in[3],
        (const float*)d_in[4],  (const float*)d_in[5],
        (const float*)d_in[6],  (const float*)d_in[7],
        (const float*)d_in[8],  (const float*)d_in[9],
        (const float*)d_in[10], (const float*)d_in[11],
        (float*)d_out);
}